// Round 15
// baseline (305.304 us; speedup 1.0000x reference)
//
#include <hip/hip_runtime.h>
#include <hip/hip_bf16.h>
#include <math.h>

constexpr int B = 256, NN = 512, EE = 511;

// ---- workspace layout (fp32 element offsets) ----
constexpr size_t F_NF    = 0;                               // node_feat  B*N*64
constexpr size_t F_EF    = F_NF   + (size_t)B*NN*64;        // edge_feat  B*E*16
constexpr size_t F_WCK   = F_EF   + (size_t)B*EE*16;        // fused K weight 144x256
constexpr size_t F_BCK   = F_WCK  + 144*256;
constexpr size_t F_WCV   = F_BCK  + 256;                    // fused V weight 144x256
constexpr size_t F_BCV   = F_WCV  + 144*256;
constexpr size_t F_WQ2   = F_BCV  + 256;                    // fused Q weight 64x256
constexpr size_t F_BQ2   = F_WQ2  + 64*256;
constexpr size_t F_Q     = F_BQ2  + 256;                    // (unused; kept for layout stability)
constexpr size_t F_AW    = F_Q    + (size_t)B*256;          // per (b,h) score weights 80
constexpr size_t F_C0    = F_AW   + (size_t)B*4*80;         // per (b,h) score const
constexpr size_t F_SC    = F_C0   + (size_t)B*4;            // scores B*4*E (dead after k_attn)
constexpr size_t F_US    = F_SC   + (size_t)B*4*EE;         // weighted sums B*4*80
constexpr size_t F_CEGO  = F_US   + (size_t)B*4*80;         // (dead, layout only)
constexpr size_t F_CVEC  = F_CEGO + (size_t)B*256;          // cvec  B*256
constexpr size_t F_SC2   = F_CVEC + (size_t)B*256;          // edge scores B*E
constexpr size_t F_ALPHA = F_SC2  + (size_t)B*EE;           // B*5
constexpr size_t F_TKI   = F_ALPHA+ (size_t)B*5;            // B*5 (ints)
constexpr size_t F_HS    = F_SC;                            // selected hidden B*5*256 (aliases dead F_SC)

// ---- output layout (fp32 elements) ----
constexpr size_t O_HEGO  = 0;          // B*256
constexpr size_t O_SEL   = 65536;      // B*5*6*256
constexpr size_t O_TKI   = 2031616;    // B*5
constexpr size_t O_ALPHA = 2032896;    // B*5

// =============== weight fusion (round-8 anchor version) ===============
__global__ void k_fuse(const float* Wkv, const float* bkv, const float* Wik, const float* bik,
                       const float* Wiv, const float* biv, const float* Wq,  const float* bq,
                       const float* Wiq, const float* biq, float* ws){
  int t = blockIdx.x*256 + threadIdx.x;
  if (t < 36864){
    int r = t >> 8, c = t & 255;
    float a = 0.f;
    for (int m=0;m<256;m++) a += Wkv[(size_t)r*512+m] * Wik[(size_t)m*256+c];
    ws[F_WCK + t] = a;
  } else if (t < 37120){
    int c = t - 36864;
    float a = bik[c];
    for (int m=0;m<256;m++) a += bkv[m] * Wik[(size_t)m*256+c];
    ws[F_BCK + c] = a;
  } else if (t < 73984){
    int i = t - 37120; int r = i >> 8, c = i & 255;
    float a = 0.f;
    for (int m=0;m<256;m++) a += Wkv[(size_t)r*512+256+m] * Wiv[(size_t)m*256+c];
    ws[F_WCV + i] = a;
  } else if (t < 74240){
    int c = t - 73984;
    float a = biv[c];
    for (int m=0;m<256;m++) a += bkv[256+m] * Wiv[(size_t)m*256+c];
    ws[F_BCV + c] = a;
  } else if (t < 90624){
    int i = t - 74240; int r = i >> 8, c = i & 255;
    float a = 0.f;
    for (int m=0;m<256;m++) a += Wq[(size_t)r*256+m] * Wiq[(size_t)m*256+c];
    ws[F_WQ2 + i] = a;
  } else if (t < 90880){
    int c = t - 90624;
    float a = biq[c];
    for (int m=0;m<256;m++) a += bq[m] * Wiq[(size_t)m*256+c];
    ws[F_BQ2 + c] = a;
  }
}

// =============== node_feat = node_raw@Wn + bn ===============
__global__ void k_nf(const float* node_raw, const float* Wn, const float* bn, float* ws){
  size_t t = (size_t)blockIdx.x*256 + threadIdx.x;   // B*N*64 total
  int j = (int)(t & 63); size_t row = t >> 6;
  float a = bn[j];
  #pragma unroll
  for (int i=0;i<8;i++) a += node_raw[row*8+i] * Wn[(size_t)i*64+j];
  ws[F_NF + t] = a;
}

// =============== edge_feat = edge_raw@We + be ===============
__global__ void k_ef(const float* edge_raw, const float* We, const float* be, float* ws){
  size_t t = (size_t)blockIdx.x*256 + threadIdx.x;   // B*E*16 total
  int j = (int)(t & 15); size_t row = t >> 4;
  float a = be[j];
  #pragma unroll
  for (int i=0;i<3;i++) a += edge_raw[row*3+i] * We[(size_t)i*16+j];
  ws[F_EF + t] = a;
}

// =============== per (b,h): q (in-block), aw (80) and c0 so score = (c0 + F·aw)/8 ===============
__global__ void k_head(const int* ego_p, float* ws){
  int b = blockIdx.x >> 2, h = blockIdx.x & 3;
  int tid = threadIdx.x;
  __shared__ float qh[64];
  __shared__ float red[256];
  int ego = *ego_p;
  const float* egf = ws + F_NF + ((size_t)b*NN+ego)*64;
  if (tid < 64){
    int c = h*64 + tid;
    float a = ws[F_BQ2 + c];
    for (int i=0;i<64;i++) a += egf[i]*ws[F_WQ2 + (size_t)i*256 + c];
    qh[tid] = a;
  }
  __syncthreads();
  const float* Wck = ws + F_WCK;
  float p = 0.f;
  size_t awbase = F_AW + ((size_t)(b*4+h))*80;
  if (tid < 64){
    const float* wr = Wck + (size_t)(80+tid)*256 + h*64;
    float a=0.f; for(int d=0;d<64;d++) a += wr[d]*qh[d];
    ws[awbase + tid] = a;
  } else if (tid < 80){
    int i = tid-64;
    const float* wr = Wck + (size_t)(64+i)*256 + h*64;
    float a=0.f; for(int d=0;d<64;d++) a += wr[d]*qh[d];
    ws[awbase + 64 + i] = a;
  } else if (tid < 144){
    int j = tid-80;
    const float* wr = Wck + (size_t)j*256 + h*64;
    float a=0.f; for(int d=0;d<64;d++) a += wr[d]*qh[d];
    p = egf[j] * a;
  } else if (tid < 208){
    int d = tid-144;
    p = ws[F_BCK + h*64 + d] * qh[d];
  }
  red[tid]=p; __syncthreads();
  for (int s=128;s>0;s>>=1){ if(tid<s) red[tid]+=red[tid+s]; __syncthreads(); }
  if (tid==0) ws[F_C0 + b*4 + h] = red[0];
}

// =============== attention scores for all heads: grid (2,B), 1 edge/thread ===============
__global__ void k_scores(const int* ego_p, float* ws){
  int tile = blockIdx.x, b = blockIdx.y, tid = threadIdx.x;
  __shared__ float awz[4][80];
  __shared__ float c0s[4];
  for (int l=tid; l<320; l+=256) awz[l/80][l%80] = ws[F_AW + (size_t)b*320 + l];
  if (tid<4) c0s[tid] = ws[F_C0 + b*4 + tid];
  __syncthreads();
  int e = tile*256 + tid;
  if (e >= EE) return;
  int ego = *ego_p;
  int node = e < ego ? e : e+1;
  const float4* nr = (const float4*)(ws + F_NF + ((size_t)b*NN+node)*64);
  const float4* er = (const float4*)(ws + F_EF + ((size_t)b*EE+e)*16);
  float s[4] = {c0s[0],c0s[1],c0s[2],c0s[3]};
  #pragma unroll
  for (int i=0;i<16;i++){
    float4 x = nr[i];
    #pragma unroll
    for (int h=0;h<4;h++)
      s[h] += x.x*awz[h][i*4] + x.y*awz[h][i*4+1] + x.z*awz[h][i*4+2] + x.w*awz[h][i*4+3];
  }
  #pragma unroll
  for (int i=0;i<4;i++){
    float4 x = er[i];
    #pragma unroll
    for (int h=0;h<4;h++)
      s[h] += x.x*awz[h][64+i*4] + x.y*awz[h][64+i*4+1] + x.z*awz[h][64+i*4+2] + x.w*awz[h][64+i*4+3];
  }
  #pragma unroll
  for (int h=0;h<4;h++) ws[F_SC + ((size_t)(b*4+h))*EE + e] = s[h]*0.125f;
}

// =============== softmax + weighted sums fused, per (b,h) (round-8 anchor) ===============
__global__ void k_attn(const int* ego_p, float* ws){
  int bh = blockIdx.x; int b = bh>>2; int tid = threadIdx.x;
  __shared__ float sc[512];
  __shared__ float red[256];
  const float* s = ws + F_SC + (size_t)bh*EE;
  float v0 = tid<EE ? s[tid] : -INFINITY;
  float v1 = (tid+256)<EE ? s[tid+256] : -INFINITY;
  red[tid] = fmaxf(v0,v1); __syncthreads();
  for (int st=128;st>0;st>>=1){ if(tid<st) red[tid]=fmaxf(red[tid],red[tid+st]); __syncthreads(); }
  float m = red[0]; __syncthreads();
  float e0 = tid<EE ? expf(v0-m) : 0.f;
  float e1 = (tid+256)<EE ? expf(v1-m) : 0.f;
  red[tid] = e0+e1; __syncthreads();
  for (int st=128;st>0;st>>=1){ if(tid<st) red[tid]+=red[tid+st]; __syncthreads(); }
  float inv = 1.f/red[0];
  sc[tid] = e0*inv;
  sc[tid+256] = e1*inv;            // sc[511]=0, never read
  __syncthreads();
  int ego = *ego_p;
  if (tid < 64){
    const float* base = ws + F_NF + (size_t)b*NN*64 + tid;
    float a = 0.f;
    for (int e=0;e<EE;e++){
      int node = e<ego?e:e+1;
      a += sc[e]*base[(size_t)node*64];
    }
    ws[F_US + (size_t)bh*80 + tid] = a;
  } else if (tid < 80){
    int d = tid-64;
    const float* base = ws + F_EF + (size_t)b*EE*16 + d;
    float a = 0.f;
    for (int e=0;e<EE;e++) a += sc[e]*base[(size_t)e*16];
    ws[F_US + (size_t)bh*80 + tid] = a;
  }
}

// =============== per-b tail (round-8 anchor) ===============
__global__ void k_bfinal(const int* ego_p,
                         const float* Wo, const float* bo,
                         const float* Wf1, const float* bf1p,
                         const float* Wf2, const float* bf2p,
                         const float* Ws1, const float* bs1,
                         float* ws, float* out){
  int b = blockIdx.x, t = threadIdx.x;
  __shared__ float ego_s[64], us_s[4][80], ctx_s[256], cego_s[256], hf_s[256];
  int ego = *ego_p;
  if (t < 64) ego_s[t] = ws[F_NF + ((size_t)b*NN+ego)*64 + t];
  for (int l=t; l<320; l+=256) us_s[l/80][l%80] = ws[F_US + (size_t)b*320 + l];
  __syncthreads();
  {
    int h = t >> 6;
    const float* Wcv = ws + F_WCV;
    float a = ws[F_BCV + t];
    for (int i=0;i<64;i++) a += ego_s[i]*Wcv[(size_t)i*256+t];
    for (int i=0;i<16;i++) a += us_s[h][64+i]*Wcv[(size_t)(64+i)*256+t];
    for (int i=0;i<64;i++) a += us_s[h][i]*Wcv[(size_t)(80+i)*256+t];
    ctx_s[t]=a;
  }
  __syncthreads();
  {
    float a = bo[t];
    for (int i=0;i<256;i++) a += ctx_s[i]*Wo[(size_t)i*256+t];
    cego_s[t]=a;
  }
  __syncthreads();
  {
    float a = bf1p[t];
    for (int i=0;i<64;i++)  a += ego_s[i]*Wf1[(size_t)i*256+t];
    for (int i=0;i<256;i++) a += cego_s[i]*Wf1[(size_t)(64+i)*256+t];
    hf_s[t]=fmaxf(a,0.f);
  }
  __syncthreads();
  {
    float a = bf2p[t];
    for (int i=0;i<256;i++) a += hf_s[i]*Wf2[(size_t)i*256+t];
    out[O_HEGO + (size_t)b*256+t] = a;
  }
  {
    float a = bs1[t];
    for (int i=0;i<256;i++) a += cego_s[i]*Ws1[(size_t)(80+i)*256+t];
    ws[F_CVEC + (size_t)b*256+t]=a;
  }
}

// =============== edge score GEMM v8: thread=col, Ws1-col in registers, F via scalar pipe ===============
// v4 is LDS-issue-bound (240 b128/thread, 79.4us); v7 was L2-bound (103us). v8 removes both:
// Ws1 column (80 f32) register-resident, loaded once coalesced; F-row addresses are
// wave-UNIFORM (b, edge, ego all uniform) -> with __restrict__ split read/write pointers
// hipcc promotes them to s_load (scalar pipe). Per-edge score = 64-lane shfl reduce +
// cross-wave LDS combine. Expected ~40-50us; if >=80, scalarization failed -> revert to v4.
__global__ __launch_bounds__(256) void k_bigscore(const int* ego_p,
                        const float* __restrict__ Ws1, const float* __restrict__ Ws2,
                        const float* __restrict__ bs2,
                        const float* __restrict__ wsr, float* __restrict__ sc2){
  int tile = blockIdx.x, b = blockIdx.y;
  int tid = threadIdx.x;                  // output column 0..255
  int lane = tid & 63, wid = tid >> 6;
  __shared__ float part[4][64];
  int ego = __builtin_amdgcn_readfirstlane(*ego_p);
  float w[80];
  #pragma unroll
  for (int k=0;k<80;k++) w[k] = Ws1[(size_t)k*256 + tid];   // coalesced, once per block
  float cv  = wsr[F_CVEC + (size_t)b*256 + tid];
  float w2c = Ws2[(size_t)tid*1537];                        // Ws2[col][0]
  for (int eg=0; eg<64; eg+=4){
    int e0 = tile*64 + eg;
    int n0 = e0  <ego ? e0   : e0+1;
    int n1 = e0+1<ego ? e0+1 : e0+2;
    int n2 = e0+2<ego ? e0+2 : e0+3;
    int n3 = e0+3<ego ? e0+3 : e0+4;
    const float* __restrict__ a0 = wsr + F_NF + ((size_t)b*NN + n0)*64;
    const float* __restrict__ a1 = wsr + F_NF + ((size_t)b*NN + n1)*64;
    const float* __restrict__ a2 = wsr + F_NF + ((size_t)b*NN + n2)*64;
    const float* __restrict__ a3 = wsr + F_NF + ((size_t)b*NN + n3)*64;
    const float* __restrict__ x0 = wsr + F_EF + ((size_t)b*EE + e0  )*16;
    const float* __restrict__ x1 = wsr + F_EF + ((size_t)b*EE + e0+1)*16;
    const float* __restrict__ x2 = wsr + F_EF + ((size_t)b*EE + e0+2)*16;
    const float* __restrict__ x3 = wsr + F_EF + ((size_t)b*EE + e0+3)*16;
    float c0=0.f, c1=0.f, c2=0.f, c3=0.f;
    #pragma unroll
    for (int k=0;k<64;k++){
      float wk = w[k];
      c0 = fmaf(a0[k], wk, c0);
      c1 = fmaf(a1[k], wk, c1);
      c2 = fmaf(a2[k], wk, c2);
      c3 = fmaf(a3[k], wk, c3);
    }
    #pragma unroll
    for (int k=0;k<16;k++){
      float wk = w[64+k];
      c0 = fmaf(x0[k], wk, c0);
      c1 = fmaf(x1[k], wk, c1);
      c2 = fmaf(x2[k], wk, c2);
      c3 = fmaf(x3[k], wk, c3);
    }
    float p0 = fmaxf(c0+cv,0.f)*w2c;
    float p1 = fmaxf(c1+cv,0.f)*w2c;
    float p2 = fmaxf(c2+cv,0.f)*w2c;
    float p3 = fmaxf(c3+cv,0.f)*w2c;
    #pragma unroll
    for (int m=32;m>0;m>>=1){
      p0 += __shfl_xor(p0, m, 64);
      p1 += __shfl_xor(p1, m, 64);
      p2 += __shfl_xor(p2, m, 64);
      p3 += __shfl_xor(p3, m, 64);
    }
    if (lane == 0){
      part[wid][eg  ] = p0;
      part[wid][eg+1] = p1;
      part[wid][eg+2] = p2;
      part[wid][eg+3] = p3;
    }
  }
  __syncthreads();
  if (tid < 64){
    int e = tile*64 + tid;
    if (e < EE)
      sc2[(size_t)b*EE + e] = part[0][tid]+part[1][tid]+part[2][tid]+part[3][tid] + bs2[0];
  }
}

// =============== top-5 (round-8 anchor) ===============
__global__ void k_topk(float* ws, float* out){
  int b = blockIdx.x, tid = threadIdx.x;
  __shared__ float sv[256]; __shared__ int si[256];
  __shared__ float tv[8];   __shared__ int tix[8];
  const float* s = ws + F_SC2 + (size_t)b*EE;
  float v0 = tid<EE ? s[tid] : -INFINITY;       int i0 = tid;
  float v1 = (tid+256)<EE ? s[tid+256] : -INFINITY; int i1 = tid+256;
  for (int t=0;t<5;t++){
    float bvv; int bii;
    if (v0 > v1 || (v0==v1 && i0<i1)){ bvv=v0; bii=i0; } else { bvv=v1; bii=i1; }
    sv[tid]=bvv; si[tid]=bii; __syncthreads();
    for (int st=128; st>0; st>>=1){
      if (tid<st){
        float ov=sv[tid+st]; int oi=si[tid+st];
        if (ov > sv[tid] || (ov==sv[tid] && oi<si[tid])){ sv[tid]=ov; si[tid]=oi; }
      }
      __syncthreads();
    }
    if (tid==0){ tv[t]=sv[0]; tix[t]=si[0]; }
    __syncthreads();
    int w = tix[t];
    if (i0==w) v0=-INFINITY;
    if (i1==w) v1=-INFINITY;
    __syncthreads();
  }
  if (tid==0){
    float m = tv[0];
    float ex[5]; float sum=0.f;
    for (int t=0;t<5;t++){ ex[t]=expf(tv[t]-m); sum+=ex[t]; }
    for (int t=0;t<5;t++){
      float al = ex[t]/sum;
      ws[F_ALPHA + (size_t)b*5+t] = al;
      ((int*)(ws + F_TKI))[b*5+t] = tix[t];
      out[O_TKI   + (size_t)b*5+t] = (float)tix[t];
      out[O_ALPHA + (size_t)b*5+t] = al;
    }
  }
}

// =============== selected hidden rows: hs[b,t,:] = relu(F_sel@Ws1[:80] + cvec) ===============
__global__ void k_hid(const int* ego_p, const float* Ws1, float* ws){
  int bt = blockIdx.x;               // b*5 + t
  int b = bt/5;
  int tid = threadIdx.x;
  __shared__ float fr[80];
  int e = ((const int*)(ws+F_TKI))[bt];
  int ego = *ego_p;
  int node = e<ego ? e : e+1;
  if (tid < 64)      fr[tid] = ws[F_NF + ((size_t)b*NN+node)*64 + tid];
  else if (tid < 80) fr[tid] = ws[F_EF + ((size_t)b*EE+e)*16 + (tid-64)];
  __syncthreads();
  float a = ws[F_CVEC + (size_t)b*256 + tid];
  for (int d=0;d<80;d++) a += fr[d]*Ws1[(size_t)d*256+tid];
  ws[F_HS + (size_t)bt*256 + tid] = fmaxf(a,0.f);
}

// =============== h_enc GEMM: out_sel[b,t,n] = (hs[b,t,:]·Ws2[:,1+n] + bs2[1+n])*alpha ===============
__global__ __launch_bounds__(256) void k_enc(const float* Ws2, const float* bs2,
                                             float* ws, float* out){
  int r = blockIdx.x, g = blockIdx.y, tid = threadIdx.x;
  int n = r*256 + tid;                 // 0..1535
  __shared__ float hs[10][256];
  __shared__ float al[10];
  int b0 = g*2;
  for (int l=tid; l<10*256; l+=256)
    hs[l>>8][l&255] = ws[F_HS + ((size_t)b0*5)*256 + l];
  if (tid<10) al[tid] = ws[F_ALPHA + (size_t)b0*5 + tid];
  __syncthreads();
  float acc[10];
  #pragma unroll
  for (int i=0;i<10;i++) acc[i]=0.f;
  const float* w2p = Ws2 + 1 + n;
  for (int j=0;j<256;j+=4){
    float w0 = w2p[(size_t)(j+0)*1537];
    float w1 = w2p[(size_t)(j+1)*1537];
    float w2 = w2p[(size_t)(j+2)*1537];
    float w3 = w2p[(size_t)(j+3)*1537];
    #pragma unroll
    for (int i=0;i<10;i++){
      float4 h = *(const float4*)&hs[i][j];
      acc[i] = fmaf(h.x,w0, fmaf(h.y,w1, fmaf(h.z,w2, fmaf(h.w,w3, acc[i]))));
    }
  }
  float bb = bs2[1+n];
  #pragma unroll
  for (int i=0;i<10;i++)
    out[O_SEL + ((size_t)(b0*5+i))*1536 + n] = (acc[i]+bb)*al[i];
}

extern "C" void kernel_launch(void* const* d_in, const int* in_sizes, int n_in,
                              void* d_out, int out_size, void* d_ws, size_t ws_size,
                              hipStream_t stream){
  const float* node_raw=(const float*)d_in[0];
  const float* edge_raw=(const float*)d_in[1];
  const int*  ego_p   =(const int*)d_in[2];
  const float* Wn =(const float*)d_in[3];  const float* bn =(const float*)d_in[4];
  const float* We =(const float*)d_in[5];  const float* be =(const float*)d_in[6];
  const float* Wq =(const float*)d_in[7];  const float* bq =(const float*)d_in[8];
  const float* Wkv=(const float*)d_in[9];  const float* bkv=(const float*)d_in[10];
  const float* Wiq=(const float*)d_in[11]; const float* biq=(const float*)d_in[12];
  const float* Wik=(const float*)d_in[13]; const float* bik=(const float*)d_in[14];
  const float* Wiv=(const float*)d_in[15]; const float* biv=(const float*)d_in[16];
  const float* Wo =(const float*)d_in[17]; const float* bo =(const float*)d_in[18];
  const float* Wf1=(const float*)d_in[19]; const float* bf1p=(const float*)d_in[20];
  const float* Wf2=(const float*)d_in[21]; const float* bf2p=(const float*)d_in[22];
  const float* Ws1=(const float*)d_in[23]; const float* bs1=(const float*)d_in[24];
  const float* Ws2=(const float*)d_in[25]; const float* bs2=(const float*)d_in[26];
  float* ws=(float*)d_ws;
  float* out=(float*)d_out;

  k_fuse<<<355,256,0,stream>>>(Wkv,bkv,Wik,bik,Wiv,biv,Wq,bq,Wiq,biq,ws);
  k_nf<<<(B*NN*64)/256,256,0,stream>>>(node_raw,Wn,bn,ws);
  k_ef<<<(B*EE*16)/256,256,0,stream>>>(edge_raw,We,be,ws);
  k_head<<<B*4,256,0,stream>>>(ego_p,ws);
  k_scores<<<dim3(2,B),256,0,stream>>>(ego_p,ws);
  k_attn<<<B*4,256,0,stream>>>(ego_p,ws);
  k_bfinal<<<B,256,0,stream>>>(ego_p,Wo,bo,Wf1,bf1p,Wf2,bf2p,Ws1,bs1,ws,out);
  k_bigscore<<<dim3(8,B),256,0,stream>>>(ego_p,Ws1,Ws2,bs2,ws,ws+F_SC2);
  k_topk<<<B,256,0,stream>>>(ws,out);
  k_hid<<<B*5,256,0,stream>>>(ego_p,Ws1,ws);
  k_enc<<<dim3(6,128),256,0,stream>>>(Ws2,bs2,ws,out);
}

// Round 16
// 245.449 us; speedup vs baseline: 1.2439x; 1.2439x over previous
//
#include <hip/hip_runtime.h>
#include <hip/hip_bf16.h>
#include <math.h>

constexpr int B = 256, NN = 512, EE = 511;

// ---- workspace layout (fp32 element offsets) ----
constexpr size_t F_NF    = 0;                               // node_feat  B*N*64
constexpr size_t F_EF    = F_NF   + (size_t)B*NN*64;        // edge_feat  B*E*16
constexpr size_t F_WCK   = F_EF   + (size_t)B*EE*16;        // fused K weight 144x256
constexpr size_t F_BCK   = F_WCK  + 144*256;
constexpr size_t F_WCV   = F_BCK  + 256;                    // fused V weight 144x256
constexpr size_t F_BCV   = F_WCV  + 144*256;
constexpr size_t F_WQ2   = F_BCV  + 256;                    // fused Q weight 64x256
constexpr size_t F_BQ2   = F_WQ2  + 64*256;
constexpr size_t F_Q     = F_BQ2  + 256;                    // (unused; kept for layout stability)
constexpr size_t F_AW    = F_Q    + (size_t)B*256;          // per (b,h) score weights 80
constexpr size_t F_C0    = F_AW   + (size_t)B*4*80;         // per (b,h) score const
constexpr size_t F_SC    = F_C0   + (size_t)B*4;            // scores B*4*E (dead after k_attn)
constexpr size_t F_US    = F_SC   + (size_t)B*4*EE;         // weighted sums B*4*80
constexpr size_t F_CEGO  = F_US   + (size_t)B*4*80;         // (dead, layout only)
constexpr size_t F_CVEC  = F_CEGO + (size_t)B*256;          // cvec  B*256
constexpr size_t F_SC2   = F_CVEC + (size_t)B*256;          // edge scores B*E
constexpr size_t F_ALPHA = F_SC2  + (size_t)B*EE;           // B*5
constexpr size_t F_TKI   = F_ALPHA+ (size_t)B*5;            // B*5 (ints)
constexpr size_t F_HS    = F_SC;                            // selected hidden B*5*256 (aliases dead F_SC)

// ---- output layout (fp32 elements) ----
constexpr size_t O_HEGO  = 0;          // B*256
constexpr size_t O_SEL   = 65536;      // B*5*6*256
constexpr size_t O_TKI   = 2031616;    // B*5
constexpr size_t O_ALPHA = 2032896;    // B*5

// =============== weight fusion: Wck=WkvK@Wik, Wcv=WkvV@Wiv, Wq2=Wq@Wiq ===============
__global__ void k_fuse(const float* Wkv, const float* bkv, const float* Wik, const float* bik,
                       const float* Wiv, const float* biv, const float* Wq,  const float* bq,
                       const float* Wiq, const float* biq, float* ws){
  int t = blockIdx.x*256 + threadIdx.x;
  if (t < 36864){
    int r = t >> 8, c = t & 255;
    float a = 0.f;
    for (int m=0;m<256;m++) a += Wkv[(size_t)r*512+m] * Wik[(size_t)m*256+c];
    ws[F_WCK + t] = a;
  } else if (t < 37120){
    int c = t - 36864;
    float a = bik[c];
    for (int m=0;m<256;m++) a += bkv[m] * Wik[(size_t)m*256+c];
    ws[F_BCK + c] = a;
  } else if (t < 73984){
    int i = t - 37120; int r = i >> 8, c = i & 255;
    float a = 0.f;
    for (int m=0;m<256;m++) a += Wkv[(size_t)r*512+256+m] * Wiv[(size_t)m*256+c];
    ws[F_WCV + i] = a;
  } else if (t < 74240){
    int c = t - 73984;
    float a = biv[c];
    for (int m=0;m<256;m++) a += bkv[256+m] * Wiv[(size_t)m*256+c];
    ws[F_BCV + c] = a;
  } else if (t < 90624){
    int i = t - 74240; int r = i >> 8, c = i & 255;
    float a = 0.f;
    for (int m=0;m<256;m++) a += Wq[(size_t)r*256+m] * Wiq[(size_t)m*256+c];
    ws[F_WQ2 + i] = a;
  } else if (t < 90880){
    int c = t - 90624;
    float a = biq[c];
    for (int m=0;m<256;m++) a += bq[m] * Wiq[(size_t)m*256+c];
    ws[F_BQ2 + c] = a;
  }
}

// =============== node_feat = node_raw@Wn + bn ===============
__global__ void k_nf(const float* node_raw, const float* Wn, const float* bn, float* ws){
  size_t t = (size_t)blockIdx.x*256 + threadIdx.x;   // B*N*64 total
  int j = (int)(t & 63); size_t row = t >> 6;
  float a = bn[j];
  #pragma unroll
  for (int i=0;i<8;i++) a += node_raw[row*8+i] * Wn[(size_t)i*64+j];
  ws[F_NF + t] = a;
}

// =============== edge_feat = edge_raw@We + be ===============
__global__ void k_ef(const float* edge_raw, const float* We, const float* be, float* ws){
  size_t t = (size_t)blockIdx.x*256 + threadIdx.x;   // B*E*16 total
  int j = (int)(t & 15); size_t row = t >> 4;
  float a = be[j];
  #pragma unroll
  for (int i=0;i<3;i++) a += edge_raw[row*3+i] * We[(size_t)i*16+j];
  ws[F_EF + t] = a;
}

// =============== per (b,h): q (in-block), aw (80) and c0 so score = (c0 + F·aw)/8 ===============
__global__ void k_head(const int* ego_p, float* ws){
  int b = blockIdx.x >> 2, h = blockIdx.x & 3;
  int tid = threadIdx.x;
  __shared__ float qh[64];
  __shared__ float red[256];
  int ego = *ego_p;
  const float* egf = ws + F_NF + ((size_t)b*NN+ego)*64;
  if (tid < 64){
    int c = h*64 + tid;
    float a = ws[F_BQ2 + c];
    for (int i=0;i<64;i++) a += egf[i]*ws[F_WQ2 + (size_t)i*256 + c];
    qh[tid] = a;
  }
  __syncthreads();
  const float* Wck = ws + F_WCK;
  float p = 0.f;
  size_t awbase = F_AW + ((size_t)(b*4+h))*80;
  if (tid < 64){
    const float* wr = Wck + (size_t)(80+tid)*256 + h*64;
    float a=0.f; for(int d=0;d<64;d++) a += wr[d]*qh[d];
    ws[awbase + tid] = a;
  } else if (tid < 80){
    int i = tid-64;
    const float* wr = Wck + (size_t)(64+i)*256 + h*64;
    float a=0.f; for(int d=0;d<64;d++) a += wr[d]*qh[d];
    ws[awbase + 64 + i] = a;
  } else if (tid < 144){
    int j = tid-80;
    const float* wr = Wck + (size_t)j*256 + h*64;
    float a=0.f; for(int d=0;d<64;d++) a += wr[d]*qh[d];
    p = egf[j] * a;
  } else if (tid < 208){
    int d = tid-144;
    p = ws[F_BCK + h*64 + d] * qh[d];
  }
  red[tid]=p; __syncthreads();
  for (int s=128;s>0;s>>=1){ if(tid<s) red[tid]+=red[tid+s]; __syncthreads(); }
  if (tid==0) ws[F_C0 + b*4 + h] = red[0];
}

// =============== attention scores for all heads: grid (2,B), 1 edge/thread ===============
__global__ void k_scores(const int* ego_p, float* ws){
  int tile = blockIdx.x, b = blockIdx.y, tid = threadIdx.x;
  __shared__ float awz[4][80];
  __shared__ float c0s[4];
  for (int l=tid; l<320; l+=256) awz[l/80][l%80] = ws[F_AW + (size_t)b*320 + l];
  if (tid<4) c0s[tid] = ws[F_C0 + b*4 + tid];
  __syncthreads();
  int e = tile*256 + tid;
  if (e >= EE) return;
  int ego = *ego_p;
  int node = e < ego ? e : e+1;
  const float4* nr = (const float4*)(ws + F_NF + ((size_t)b*NN+node)*64);
  const float4* er = (const float4*)(ws + F_EF + ((size_t)b*EE+e)*16);
  float s[4] = {c0s[0],c0s[1],c0s[2],c0s[3]};
  #pragma unroll
  for (int i=0;i<16;i++){
    float4 x = nr[i];
    #pragma unroll
    for (int h=0;h<4;h++)
      s[h] += x.x*awz[h][i*4] + x.y*awz[h][i*4+1] + x.z*awz[h][i*4+2] + x.w*awz[h][i*4+3];
  }
  #pragma unroll
  for (int i=0;i<4;i++){
    float4 x = er[i];
    #pragma unroll
    for (int h=0;h<4;h++)
      s[h] += x.x*awz[h][64+i*4] + x.y*awz[h][64+i*4+1] + x.z*awz[h][64+i*4+2] + x.w*awz[h][64+i*4+3];
  }
  #pragma unroll
  for (int h=0;h<4;h++) ws[F_SC + ((size_t)(b*4+h))*EE + e] = s[h]*0.125f;
}

// =============== softmax + weighted sums fused, per (b,h) ===============
__global__ void k_attn(const int* ego_p, float* ws){
  int bh = blockIdx.x; int b = bh>>2; int tid = threadIdx.x;
  __shared__ float sc[512];
  __shared__ float red[256];
  const float* s = ws + F_SC + (size_t)bh*EE;
  float v0 = tid<EE ? s[tid] : -INFINITY;
  float v1 = (tid+256)<EE ? s[tid+256] : -INFINITY;
  red[tid] = fmaxf(v0,v1); __syncthreads();
  for (int st=128;st>0;st>>=1){ if(tid<st) red[tid]=fmaxf(red[tid],red[tid+st]); __syncthreads(); }
  float m = red[0]; __syncthreads();
  float e0 = tid<EE ? expf(v0-m) : 0.f;
  float e1 = (tid+256)<EE ? expf(v1-m) : 0.f;
  red[tid] = e0+e1; __syncthreads();
  for (int st=128;st>0;st>>=1){ if(tid<st) red[tid]+=red[tid+st]; __syncthreads(); }
  float inv = 1.f/red[0];
  sc[tid] = e0*inv;
  sc[tid+256] = e1*inv;            // sc[511]=0, never read
  __syncthreads();
  int ego = *ego_p;
  if (tid < 64){
    const float* base = ws + F_NF + (size_t)b*NN*64 + tid;
    float a = 0.f;
    for (int e=0;e<EE;e++){
      int node = e<ego?e:e+1;
      a += sc[e]*base[(size_t)node*64];
    }
    ws[F_US + (size_t)bh*80 + tid] = a;
  } else if (tid < 80){
    int d = tid-64;
    const float* base = ws + F_EF + (size_t)b*EE*16 + d;
    float a = 0.f;
    for (int e=0;e<EE;e++) a += sc[e]*base[(size_t)e*16];
    ws[F_US + (size_t)bh*80 + tid] = a;
  }
}

// =============== per-b tail: ctx -> c_ego -> h_ego_prime(out) + cvec ===============
__global__ void k_bfinal(const int* ego_p,
                         const float* Wo, const float* bo,
                         const float* Wf1, const float* bf1p,
                         const float* Wf2, const float* bf2p,
                         const float* Ws1, const float* bs1,
                         float* ws, float* out){
  int b = blockIdx.x, t = threadIdx.x;
  __shared__ float ego_s[64], us_s[4][80], ctx_s[256], cego_s[256], hf_s[256];
  int ego = *ego_p;
  if (t < 64) ego_s[t] = ws[F_NF + ((size_t)b*NN+ego)*64 + t];
  for (int l=t; l<320; l+=256) us_s[l/80][l%80] = ws[F_US + (size_t)b*320 + l];
  __syncthreads();
  {
    int h = t >> 6;
    const float* Wcv = ws + F_WCV;
    float a = ws[F_BCV + t];
    for (int i=0;i<64;i++) a += ego_s[i]*Wcv[(size_t)i*256+t];
    for (int i=0;i<16;i++) a += us_s[h][64+i]*Wcv[(size_t)(64+i)*256+t];
    for (int i=0;i<64;i++) a += us_s[h][i]*Wcv[(size_t)(80+i)*256+t];
    ctx_s[t]=a;
  }
  __syncthreads();
  {
    float a = bo[t];
    for (int i=0;i<256;i++) a += ctx_s[i]*Wo[(size_t)i*256+t];
    cego_s[t]=a;
  }
  __syncthreads();
  {
    float a = bf1p[t];
    for (int i=0;i<64;i++)  a += ego_s[i]*Wf1[(size_t)i*256+t];
    for (int i=0;i<256;i++) a += cego_s[i]*Wf1[(size_t)(64+i)*256+t];
    hf_s[t]=fmaxf(a,0.f);
  }
  __syncthreads();
  {
    float a = bf2p[t];
    for (int i=0;i<256;i++) a += hf_s[i]*Wf2[(size_t)i*256+t];
    out[O_HEGO + (size_t)b*256+t] = a;
  }
  {
    float a = bs1[t];
    for (int i=0;i<256;i++) a += cego_s[i]*Ws1[(size_t)(80+i)*256+t];
    ws[F_CVEC + (size_t)b*256+t]=a;
  }
}

// =============== edge score GEMM (v4, measured-best 79.4us): conflict-free 16B-stride B ===============
// Exploration ledger: v5 dbuf=120 (occupancy), v6 8x8=104 (VGPR distribution), v7 global-B=103
// (L2 BW), v8 reg-col=144 (spill + no scalarization). v4 is the local optimum: LDS-issue-bound
// at 2.3x the 34us FMA floor.
__global__ __launch_bounds__(512) void k_bigscore(const int* ego_p, const float* Ws1,
                                                  const float* Ws2, const float* bs2, float* ws){
  int tile = blockIdx.x, b = blockIdx.y;
  int tid = threadIdx.x;
  __shared__ float Fe[64][80];          // 20 KB, [edge][k]
  __shared__ float Bs[16][256];         // 16 KB, k-chunk of Ws1
  __shared__ float cv_s[256], w2_s[256];
  int ego = *ego_p;
  if (tid < 256){
    cv_s[tid] = ws[F_CVEC + (size_t)b*256 + tid];
    w2_s[tid] = Ws2[(size_t)tid*1537];          // Ws2[:,0]
  }
  for (int l=tid; l<80*64; l+=512){
    int e = l/80, k = l - e*80;
    int eg = tile*64 + e;
    float v = 0.f;
    if (eg < EE){
      int node = eg<ego?eg:eg+1;
      v = (k<64) ? ws[F_NF + ((size_t)b*NN+node)*64 + k]
                 : ws[F_EF + ((size_t)b*EE+eg)*16 + (k-64)];
    }
    Fe[e][k] = v;
  }
  int tc = tid & 31, te = tid >> 5;
  float acc[4][8];
  #pragma unroll
  for (int i=0;i<4;i++)
    #pragma unroll
    for (int j=0;j<8;j++) acc[i][j]=0.f;

  for (int c=0;c<5;c++){
    __syncthreads();
    {
      float4* dst = (float4*)&Bs[0][0];
      const float4* s4 = (const float4*)(Ws1 + (size_t)(c*16)*256);
      dst[tid]       = s4[tid];
      dst[tid + 512] = s4[tid + 512];
    }
    __syncthreads();
    #pragma unroll
    for (int kk=0; kk<16; kk+=4){
      float A[4][4];
      #pragma unroll
      for (int i=0;i<4;i++){
        float4 t4 = *(const float4*)&Fe[te*4+i][c*16+kk];
        A[i][0]=t4.x; A[i][1]=t4.y; A[i][2]=t4.z; A[i][3]=t4.w;
      }
      #pragma unroll
      for (int q=0;q<4;q++){
        float4 b0 = *(const float4*)&Bs[kk+q][tc*4];
        float4 b1 = *(const float4*)&Bs[kk+q][128 + tc*4];
        float bw[8] = {b0.x,b0.y,b0.z,b0.w,b1.x,b1.y,b1.z,b1.w};
        #pragma unroll
        for (int i=0;i<4;i++)
          #pragma unroll
          for (int j=0;j<8;j++) acc[i][j] = fmaf(A[i][q], bw[j], acc[i][j]);
      }
    }
  }
  float bs20 = bs2[0];
  #pragma unroll
  for (int i=0;i<4;i++){
    float p = 0.f;
    #pragma unroll
    for (int j=0;j<4;j++){
      int col = tc*4 + j;
      float hcol = acc[i][j] + cv_s[col];
      p += fmaxf(hcol,0.f)*w2_s[col];
    }
    #pragma unroll
    for (int j=0;j<4;j++){
      int col = 128 + tc*4 + j;
      float hcol = acc[i][4+j] + cv_s[col];
      p += fmaxf(hcol,0.f)*w2_s[col];
    }
    #pragma unroll
    for (int m=16;m>0;m>>=1) p += __shfl_xor(p, m, 64);
    if (tc==0){
      int eg = tile*64 + te*4 + i;
      if (eg < EE) ws[F_SC2 + (size_t)b*EE + eg] = p + bs20;
    }
  }
}

// =============== top-5 (stable, ties -> lower index) + alpha softmax ===============
__global__ void k_topk(float* ws, float* out){
  int b = blockIdx.x, tid = threadIdx.x;
  __shared__ float sv[256]; __shared__ int si[256];
  __shared__ float tv[8];   __shared__ int tix[8];
  const float* s = ws + F_SC2 + (size_t)b*EE;
  float v0 = tid<EE ? s[tid] : -INFINITY;       int i0 = tid;
  float v1 = (tid+256)<EE ? s[tid+256] : -INFINITY; int i1 = tid+256;
  for (int t=0;t<5;t++){
    float bvv; int bii;
    if (v0 > v1 || (v0==v1 && i0<i1)){ bvv=v0; bii=i0; } else { bvv=v1; bii=i1; }
    sv[tid]=bvv; si[tid]=bii; __syncthreads();
    for (int st=128; st>0; st>>=1){
      if (tid<st){
        float ov=sv[tid+st]; int oi=si[tid+st];
        if (ov > sv[tid] || (ov==sv[tid] && oi<si[tid])){ sv[tid]=ov; si[tid]=oi; }
      }
      __syncthreads();
    }
    if (tid==0){ tv[t]=sv[0]; tix[t]=si[0]; }
    __syncthreads();
    int w = tix[t];
    if (i0==w) v0=-INFINITY;
    if (i1==w) v1=-INFINITY;
    __syncthreads();
  }
  if (tid==0){
    float m = tv[0];
    float ex[5]; float sum=0.f;
    for (int t=0;t<5;t++){ ex[t]=expf(tv[t]-m); sum+=ex[t]; }
    for (int t=0;t<5;t++){
      float al = ex[t]/sum;
      ws[F_ALPHA + (size_t)b*5+t] = al;
      ((int*)(ws + F_TKI))[b*5+t] = tix[t];
      out[O_TKI   + (size_t)b*5+t] = (float)tix[t];
      out[O_ALPHA + (size_t)b*5+t] = al;
    }
  }
}

// =============== selected hidden rows: hs[b,t,:] = relu(F_sel@Ws1[:80] + cvec) ===============
__global__ void k_hid(const int* ego_p, const float* Ws1, float* ws){
  int bt = blockIdx.x;               // b*5 + t
  int b = bt/5;
  int tid = threadIdx.x;
  __shared__ float fr[80];
  int e = ((const int*)(ws+F_TKI))[bt];
  int ego = *ego_p;
  int node = e<ego ? e : e+1;
  if (tid < 64)      fr[tid] = ws[F_NF + ((size_t)b*NN+node)*64 + tid];
  else if (tid < 80) fr[tid] = ws[F_EF + ((size_t)b*EE+e)*16 + (tid-64)];
  __syncthreads();
  float a = ws[F_CVEC + (size_t)b*256 + tid];
  for (int d=0;d<80;d++) a += fr[d]*Ws1[(size_t)d*256+tid];
  ws[F_HS + (size_t)bt*256 + tid] = fmaxf(a,0.f);
}

// =============== h_enc GEMM: out_sel[b,t,n] = (hs[b,t,:]·Ws2[:,1+n] + bs2[1+n])*alpha ===============
__global__ __launch_bounds__(256) void k_enc(const float* Ws2, const float* bs2,
                                             float* ws, float* out){
  int r = blockIdx.x, g = blockIdx.y, tid = threadIdx.x;
  int n = r*256 + tid;                 // 0..1535
  __shared__ float hs[10][256];
  __shared__ float al[10];
  int b0 = g*2;
  for (int l=tid; l<10*256; l+=256)
    hs[l>>8][l&255] = ws[F_HS + ((size_t)b0*5)*256 + l];
  if (tid<10) al[tid] = ws[F_ALPHA + (size_t)b0*5 + tid];
  __syncthreads();
  float acc[10];
  #pragma unroll
  for (int i=0;i<10;i++) acc[i]=0.f;
  const float* w2p = Ws2 + 1 + n;
  for (int j=0;j<256;j+=4){
    float w0 = w2p[(size_t)(j+0)*1537];
    float w1 = w2p[(size_t)(j+1)*1537];
    float w2 = w2p[(size_t)(j+2)*1537];
    float w3 = w2p[(size_t)(j+3)*1537];
    #pragma unroll
    for (int i=0;i<10;i++){
      float4 h = *(const float4*)&hs[i][j];
      acc[i] = fmaf(h.x,w0, fmaf(h.y,w1, fmaf(h.z,w2, fmaf(h.w,w3, acc[i]))));
    }
  }
  float bb = bs2[1+n];
  #pragma unroll
  for (int i=0;i<10;i++)
    out[O_SEL + ((size_t)(b0*5+i))*1536 + n] = (acc[i]+bb)*al[i];
}

extern "C" void kernel_launch(void* const* d_in, const int* in_sizes, int n_in,
                              void* d_out, int out_size, void* d_ws, size_t ws_size,
                              hipStream_t stream){
  const float* node_raw=(const float*)d_in[0];
  const float* edge_raw=(const float*)d_in[1];
  const int*  ego_p   =(const int*)d_in[2];
  const float* Wn =(const float*)d_in[3];  const float* bn =(const float*)d_in[4];
  const float* We =(const float*)d_in[5];  const float* be =(const float*)d_in[6];
  const float* Wq =(const float*)d_in[7];  const float* bq =(const float*)d_in[8];
  const float* Wkv=(const float*)d_in[9];  const float* bkv=(const float*)d_in[10];
  const float* Wiq=(const float*)d_in[11]; const float* biq=(const float*)d_in[12];
  const float* Wik=(const float*)d_in[13]; const float* bik=(const float*)d_in[14];
  const float* Wiv=(const float*)d_in[15]; const float* biv=(const float*)d_in[16];
  const float* Wo =(const float*)d_in[17]; const float* bo =(const float*)d_in[18];
  const float* Wf1=(const float*)d_in[19]; const float* bf1p=(const float*)d_in[20];
  const float* Wf2=(const float*)d_in[21]; const float* bf2p=(const float*)d_in[22];
  const float* Ws1=(const float*)d_in[23]; const float* bs1=(const float*)d_in[24];
  const float* Ws2=(const float*)d_in[25]; const float* bs2=(const float*)d_in[26];
  float* ws=(float*)d_ws;
  float* out=(float*)d_out;

  k_fuse<<<355,256,0,stream>>>(Wkv,bkv,Wik,bik,Wiv,biv,Wq,bq,Wiq,biq,ws);
  k_nf<<<(B*NN*64)/256,256,0,stream>>>(node_raw,Wn,bn,ws);
  k_ef<<<(B*EE*16)/256,256,0,stream>>>(edge_raw,We,be,ws);
  k_head<<<B*4,256,0,stream>>>(ego_p,ws);
  k_scores<<<dim3(2,B),256,0,stream>>>(ego_p,ws);
  k_attn<<<B*4,256,0,stream>>>(ego_p,ws);
  k_bfinal<<<B,256,0,stream>>>(ego_p,Wo,bo,Wf1,bf1p,Wf2,bf2p,Ws1,bs1,ws,out);
  k_bigscore<<<dim3(8,B),512,0,stream>>>(ego_p,Ws1,Ws2,bs2,ws);
  k_topk<<<B,256,0,stream>>>(ws,out);
  k_hid<<<B*5,256,0,stream>>>(ego_p,Ws1,ws);
  k_enc<<<dim3(6,128),256,0,stream>>>(Ws2,bs2,ws,out);
}